// Round 9
// baseline (1151.592 us; speedup 1.0000x reference)
//
#include <hip/hip_runtime.h>

#define B_  64
#define S_  128
#define H_  1024
#define V_  32000
#define T_  10

typedef unsigned short ushort_t;
typedef unsigned int uint32;
typedef __attribute__((ext_vector_type(8))) short bf16x8;
typedef __attribute__((ext_vector_type(4))) float f32x4;

__device__ __forceinline__ ushort_t f2bf(float x) {
    uint32 u = __float_as_uint(x);
    u += 0x7fffu + ((u >> 16) & 1u);
    return (ushort_t)(u >> 16);
}
__device__ __forceinline__ float bf2f(ushort_t h) {
    return __uint_as_float(((uint32)h) << 16);
}
__device__ __forceinline__ uint32 pk2(float a, float b) {
    return (uint32)f2bf(a) | ((uint32)f2bf(b) << 16);
}

typedef const __attribute__((address_space(1))) void gas_void;
typedef __attribute__((address_space(3))) void las_void;
__device__ __forceinline__ void gload_lds16(const ushort_t* g, ushort_t* l) {
    __builtin_amdgcn_global_load_lds((gas_void*)g, (las_void*)l, 16, 0, 0);
}

// ---------------------------------------------------------------------------
// bf16 MFMA GEMM: C[M,N] = A @ Bt^T (+bias). All operands pre-cast bf16 hi(/lo),
// staged via global_load_lds (16B). SPLIT: 3-MFMA hi/lo (~fp32 accuracy).
// Split-K via blockIdx.z -> C + z*czstride.
// SWZ: 0 none; 1 XCD owns m-chunk (m = w/gridX); 2 XCD owns n-chunk (m = w%gridY).
//      w = bijective chunk remap of lin with q = nwg/8, r = nwg%8 (m204).
// CMODE 0: C[gr*ldc+col] = acc (+bias)   CMODE 2: logits scatter row t*64+b -> [b,t,:]
// ---------------------------------------------------------------------------
template<int BM, int BN, int WC, bool SPLIT, int CMODE, int SWZ>
__launch_bounds__(256)
__global__ void gemm_bf(const ushort_t* __restrict__ Ah, const ushort_t* __restrict__ Al,
                        int lda,
                        const ushort_t* __restrict__ Bh, const ushort_t* __restrict__ Bl,
                        int ldb,
                        int K, int kchunk,
                        const float* __restrict__ bias,
                        float* __restrict__ C, int ldc, size_t czstride,
                        int swz_q, int swz_r)
{
    constexpr int WR = 4 / WC;
    constexpr int MF = BM / WR / 16;
    constexpr int NF = BN / WC / 16;
    __shared__ __align__(16) ushort_t lds[(SPLIT ? 2 : 1) * (BM + BN) * 32];
    ushort_t* ldsAh = lds;
    ushort_t* ldsAl = lds + BM * 32;
    ushort_t* ldsBh = lds + (SPLIT ? 2 : 1) * BM * 32;
    ushort_t* ldsBl = ldsBh + BN * 32;

    const int tid  = threadIdx.x;
    const int wid  = tid >> 6;
    const int lane = tid & 63;
    const int lr   = lane & 15;
    const int lk   = lane >> 4;

    int m_i, n_i;
    if (SWZ == 0) {
        m_i = blockIdx.y; n_i = blockIdx.x;
    } else {
        int lin = blockIdx.y * gridDim.x + blockIdx.x;
        int xcd = lin & 7, idx = lin >> 3;
        int w = (xcd < swz_r) ? xcd * (swz_q + 1) + idx
                              : swz_r * (swz_q + 1) + (xcd - swz_r) * swz_q + idx;
        if (SWZ == 1) { m_i = w / (int)gridDim.x; n_i = w % (int)gridDim.x; }
        else          { m_i = w % (int)gridDim.y; n_i = w / (int)gridDim.y; }
    }
    const int m0 = m_i * BM;
    const int n0 = n_i * BN;

    const int wrow = wid / WC, wcol = wid % WC;
    const int mW   = wrow * (BM / WR);
    const int nW   = wcol * (BN / WC);

    f32x4 acc[MF][NF];
    #pragma unroll
    for (int i = 0; i < MF; i++)
        #pragma unroll
        for (int j = 0; j < NF; j++)
            acc[i][j] = (f32x4){0.f, 0.f, 0.f, 0.f};

    const int kbeg = blockIdx.z * kchunk;
    const int kend = (kbeg + kchunk < K) ? (kbeg + kchunk) : K;

    for (int k0 = kbeg; k0 < kend; k0 += 32) {
        __syncthreads();
        for (int is = wid; is < BM / 16; is += 4) {
            int row = is * 16 + (lane >> 2), chk = lane & 3;
            size_t off = (size_t)(m0 + row) * lda + k0 + chk * 8;
            gload_lds16(Ah + off, &ldsAh[is * 512]);
            if constexpr (SPLIT) gload_lds16(Al + off, &ldsAl[is * 512]);
        }
        for (int is = wid; is < BN / 16; is += 4) {
            int row = is * 16 + (lane >> 2), chk = lane & 3;
            size_t off = (size_t)(n0 + row) * ldb + k0 + chk * 8;
            gload_lds16(Bh + off, &ldsBh[is * 512]);
            if constexpr (SPLIT) gload_lds16(Bl + off, &ldsBl[is * 512]);
        }
        __syncthreads();
        bf16x8 aH[MF], bH[NF], aL[MF], bL[NF];
        #pragma unroll
        for (int i = 0; i < MF; i++) {
            aH[i] = *(const bf16x8*)&ldsAh[(mW + i * 16 + lr) * 32 + lk * 8];
            if constexpr (SPLIT) aL[i] = *(const bf16x8*)&ldsAl[(mW + i * 16 + lr) * 32 + lk * 8];
        }
        #pragma unroll
        for (int j = 0; j < NF; j++) {
            bH[j] = *(const bf16x8*)&ldsBh[(nW + j * 16 + lr) * 32 + lk * 8];
            if constexpr (SPLIT) bL[j] = *(const bf16x8*)&ldsBl[(nW + j * 16 + lr) * 32 + lk * 8];
        }
        #pragma unroll
        for (int i = 0; i < MF; i++)
            #pragma unroll
            for (int j = 0; j < NF; j++) {
                acc[i][j] = __builtin_amdgcn_mfma_f32_16x16x32_bf16(aH[i], bH[j], acc[i][j], 0, 0, 0);
                if constexpr (SPLIT) {
                    acc[i][j] = __builtin_amdgcn_mfma_f32_16x16x32_bf16(aH[i], bL[j], acc[i][j], 0, 0, 0);
                    acc[i][j] = __builtin_amdgcn_mfma_f32_16x16x32_bf16(aL[i], bH[j], acc[i][j], 0, 0, 0);
                }
            }
    }
    float* Cz = C + (size_t)blockIdx.z * czstride;
    #pragma unroll
    for (int i = 0; i < MF; i++)
        #pragma unroll
        for (int j = 0; j < NF; j++)
            #pragma unroll
            for (int r = 0; r < 4; r++) {
                int gr  = m0 + mW + i * 16 + lk * 4 + r;
                int col = n0 + nW + j * 16 + lr;
                float v = acc[i][j][r];
                if (CMODE == 0) {
                    if (bias) v += bias[col];
                    Cz[(size_t)gr * ldc + col] = v;
                } else {
                    int b = gr & 63, t = gr >> 6;
                    C[((size_t)(b * T_ + t)) * V_ + col] = v + bias[col];
                }
            }
}

// ---------------------------------------------------------------------------
// Fused gi2 = ctx @ W_ih[:, H:]^T (SPLIT) + GRU combine. One block = 32 g-cols,
// all 3 gates (BN=96), all 64 b (BM=64), full K=1024. Writes H_hi/H_lo(t+1).
// ---------------------------------------------------------------------------
__launch_bounds__(256)
__global__ void gigru_k(const ushort_t* __restrict__ ctx_hi, const ushort_t* __restrict__ ctx_lo,
                        const ushort_t* __restrict__ W2h, const ushort_t* __restrict__ W2l, // Wih + H_, ldb 2H
                        const float* __restrict__ giemb_t,
                        const float* __restrict__ qgh_part,
                        const float* __restrict__ b_hh,
                        ushort_t* __restrict__ Hh, ushort_t* __restrict__ Hl,
                        int t, float* __restrict__ out_hidden)
{
    constexpr int BM = 64, BN = 96;
    __shared__ __align__(16) ushort_t lds[(BM + BN) * 32 * 2];   // Ah,Al,Bh,Bl = 20 KB
    __shared__ float gi_lds[64][97];                              // 24.8 KB
    ushort_t* ldsAh = lds;
    ushort_t* ldsAl = lds + BM * 32;
    ushort_t* ldsBh = lds + 2 * BM * 32;
    ushort_t* ldsBl = ldsBh + BN * 32;

    const int tid = threadIdx.x, wid = tid >> 6, lane = tid & 63;
    const int lr = lane & 15, lk = lane >> 4;
    const int g0 = blockIdx.x * 32;
    const int wr = wid >> 1, wc = wid & 1;      // 2x2 waves: 32 rows x 48 cols each
    const int mW = wr * 32, nW = wc * 48;

    f32x4 acc[2][3];
    #pragma unroll
    for (int i = 0; i < 2; i++)
        #pragma unroll
        for (int j = 0; j < 3; j++)
            acc[i][j] = (f32x4){0.f, 0.f, 0.f, 0.f};

    for (int k0 = 0; k0 < H_; k0 += 32) {
        __syncthreads();
        {   // A: ctx [64][H]
            int row = wid * 16 + (lane >> 2);
            size_t off = (size_t)row * H_ + k0 + (lane & 3) * 8;
            gload_lds16(ctx_hi + off, &ldsAh[wid * 512]);
            gload_lds16(ctx_lo + off, &ldsAl[wid * 512]);
        }
        for (int is = wid; is < 6; is += 4) {   // B: rows gate*1024 + g0 + gl
            int br = is * 16 + (lane >> 2);
            int grow = (br >> 5) * H_ + g0 + (br & 31);
            size_t off = (size_t)grow * (2 * H_) + k0 + (lane & 3) * 8;
            gload_lds16(W2h + off, &ldsBh[is * 512]);
            gload_lds16(W2l + off, &ldsBl[is * 512]);
        }
        __syncthreads();
        bf16x8 aH[2], aL[2], bH[3], bL[3];
        #pragma unroll
        for (int i = 0; i < 2; i++) {
            aH[i] = *(const bf16x8*)&ldsAh[(mW + i * 16 + lr) * 32 + lk * 8];
            aL[i] = *(const bf16x8*)&ldsAl[(mW + i * 16 + lr) * 32 + lk * 8];
        }
        #pragma unroll
        for (int j = 0; j < 3; j++) {
            bH[j] = *(const bf16x8*)&ldsBh[(nW + j * 16 + lr) * 32 + lk * 8];
            bL[j] = *(const bf16x8*)&ldsBl[(nW + j * 16 + lr) * 32 + lk * 8];
        }
        #pragma unroll
        for (int i = 0; i < 2; i++)
            #pragma unroll
            for (int j = 0; j < 3; j++) {
                acc[i][j] = __builtin_amdgcn_mfma_f32_16x16x32_bf16(aH[i], bH[j], acc[i][j], 0, 0, 0);
                acc[i][j] = __builtin_amdgcn_mfma_f32_16x16x32_bf16(aH[i], bL[j], acc[i][j], 0, 0, 0);
                acc[i][j] = __builtin_amdgcn_mfma_f32_16x16x32_bf16(aL[i], bH[j], acc[i][j], 0, 0, 0);
            }
    }
    __syncthreads();
    #pragma unroll
    for (int i = 0; i < 2; i++)
        #pragma unroll
        for (int j = 0; j < 3; j++)
            #pragma unroll
            for (int r = 0; r < 4; r++)
                gi_lds[mW + i * 16 + lk * 4 + r][nW + j * 16 + lr] = acc[i][j][r];
    __syncthreads();
    // GRU: 64 b x 32 g cells; 8 per thread
    #pragma unroll
    for (int kk = 0; kk < 8; kk++) {
        int c = kk * 256 + tid;
        int gl = c & 31, b = c >> 5;
        int g = g0 + gl;
        float ir = giemb_t[(size_t)b * 3072 + g]        + gi_lds[b][gl];
        float iz = giemb_t[(size_t)b * 3072 + 1024 + g] + gi_lds[b][32 + gl];
        float in = giemb_t[(size_t)b * 3072 + 2048 + g] + gi_lds[b][64 + gl];
        float hr = b_hh[g], hz = b_hh[1024 + g], hn_ = b_hh[2048 + g];
        #pragma unroll
        for (int kz = 0; kz < 4; kz++) {
            const float* qp = qgh_part + (size_t)kz * B_ * 4096 + (size_t)b * 4096 + 1024;
            hr += qp[g]; hz += qp[1024 + g]; hn_ += qp[2048 + g];
        }
        size_t ih = (size_t)t * B_ * H_ + (size_t)b * H_ + g;
        float h = bf2f(Hh[ih]) + bf2f(Hl[ih]);
        float r = 1.f / (1.f + expf(-(ir + hr)));
        float z = 1.f / (1.f + expf(-(iz + hz)));
        float n = tanhf(in + r * hn_);
        float hn = (1.f - z) * n + z * h;
        ushort_t hih = f2bf(hn);
        Hh[ih + B_ * H_] = hih;
        Hl[ih + B_ * H_] = f2bf(hn - bf2f(hih));
        if (out_hidden) out_hidden[(size_t)b * H_ + g] = hn;
    }
}

// ---------------------------------------------------------------------------
__global__ __launch_bounds__(256) void cast_bf16_k(const float* __restrict__ in,
                                                   ushort_t* __restrict__ out, int n8)
{
    int i = blockIdx.x * 256 + threadIdx.x;
    if (i < n8) {
        float4 a = ((const float4*)in)[2 * i];
        float4 b = ((const float4*)in)[2 * i + 1];
        uint4 v;
        v.x = pk2(a.x, a.y); v.y = pk2(a.z, a.w);
        v.z = pk2(b.x, b.y); v.w = pk2(b.z, b.w);
        ((uint4*)out)[i] = v;
    }
}

// merged hi/lo cast: {enc, Ua, Wih, Wa, Whh, hidden} -> contiguous HI / LO blocks
#define CAN0 1048576
#define CAN1 131072
#define CAN2 786432
#define CAN3 131072
#define CAN4 393216
#define CAN5 8192
#define CAC1 (CAN0)
#define CAC2 (CAC1+CAN1)
#define CAC3 (CAC2+CAN2)
#define CAC4 (CAC3+CAN3)
#define CAC5 (CAC4+CAN4)
#define CATOT (CAC5+CAN5)
__global__ __launch_bounds__(256) void castall_k(const float* __restrict__ s0,
                                                 const float* __restrict__ s1,
                                                 const float* __restrict__ s2,
                                                 const float* __restrict__ s3,
                                                 const float* __restrict__ s4,
                                                 const float* __restrict__ s5,
                                                 ushort_t* __restrict__ hi,
                                                 ushort_t* __restrict__ lo)
{
    for (int i = blockIdx.x * 256 + threadIdx.x; i < CATOT; i += gridDim.x * 256) {
        const float* s; int j;
        if      (i < CAC1) { s = s0; j = i; }
        else if (i < CAC2) { s = s1; j = i - CAC1; }
        else if (i < CAC3) { s = s2; j = i - CAC2; }
        else if (i < CAC4) { s = s3; j = i - CAC3; }
        else if (i < CAC5) { s = s4; j = i - CAC4; }
        else               { s = s5; j = i - CAC5; }
        float4 a = ((const float4*)s)[2 * j];
        float4 b = ((const float4*)s)[2 * j + 1];
        uint4 hv, lv;
        hv.x = pk2(a.x, a.y); hv.y = pk2(a.z, a.w);
        hv.z = pk2(b.x, b.y); hv.w = pk2(b.z, b.w);
        lv.x = pk2(a.x - bf2f((ushort_t)(hv.x & 0xffff)), a.y - bf2f((ushort_t)(hv.x >> 16)));
        lv.y = pk2(a.z - bf2f((ushort_t)(hv.y & 0xffff)), a.w - bf2f((ushort_t)(hv.y >> 16)));
        lv.z = pk2(b.x - bf2f((ushort_t)(hv.z & 0xffff)), b.y - bf2f((ushort_t)(hv.z >> 16)));
        lv.w = pk2(b.z - bf2f((ushort_t)(hv.w & 0xffff)), b.w - bf2f((ushort_t)(hv.w >> 16)));
        ((uint4*)hi)[i] = hv;
        ((uint4*)lo)[i] = lv;
    }
}

// gather teacher-forced embeddings -> hi/lo bf16, rows r = t*64+b
__global__ __launch_bounds__(256) void gatherhl_k(const int* __restrict__ target,
                                                  const float* __restrict__ emb_W,
                                                  ushort_t* __restrict__ Eh,
                                                  ushort_t* __restrict__ El)
{
    int idx = blockIdx.x * 256 + threadIdx.x;
    int r = idx >> 7, c8 = idx & 127;
    int t = r >> 6, b = r & 63;
    int tok = (t == 0) ? 0 : target[b * T_ + t - 1];
    const float* src = emb_W + (size_t)tok * H_ + c8 * 8;
    float4 a = *(const float4*)src;
    float4 c = *(const float4*)(src + 4);
    uint4 hv, lv;
    hv.x = pk2(a.x, a.y); hv.y = pk2(a.z, a.w);
    hv.z = pk2(c.x, c.y); hv.w = pk2(c.z, c.w);
    lv.x = pk2(a.x - bf2f((ushort_t)(hv.x & 0xffff)), a.y - bf2f((ushort_t)(hv.x >> 16)));
    lv.y = pk2(a.z - bf2f((ushort_t)(hv.y & 0xffff)), a.w - bf2f((ushort_t)(hv.y >> 16)));
    lv.z = pk2(c.x - bf2f((ushort_t)(hv.z & 0xffff)), c.y - bf2f((ushort_t)(hv.z >> 16)));
    lv.w = pk2(c.z - bf2f((ushort_t)(hv.w & 0xffff)), c.w - bf2f((ushort_t)(hv.w >> 16)));
    ((uint4*)(Eh + (size_t)r * H_))[c8] = hv;
    ((uint4*)(El + (size_t)r * H_))[c8] = lv;
}

// score[b,s] = Va . tanh(q[b]+Uk[b,s]) + Va_b ; q = sum_kz qgh_part + Wa_b
__global__ __launch_bounds__(256) void score_k(const float* __restrict__ Uk,
                                               const float* __restrict__ qgh_part,
                                               const float* __restrict__ Wa_b,
                                               const float* __restrict__ Va_w,
                                               const float* __restrict__ Va_b,
                                               float* __restrict__ scores)
{
    int s = blockIdx.x, b = blockIdx.y;
    int tid = threadIdx.x;
    float4 qq = ((const float4*)Wa_b)[tid];
    #pragma unroll
    for (int kz = 0; kz < 4; kz++) {
        float4 p = ((const float4*)(qgh_part + (size_t)kz * B_ * 4096 + (size_t)b * 4096))[tid];
        qq.x += p.x; qq.y += p.y; qq.z += p.z; qq.w += p.w;
    }
    float4 u = ((const float4*)(Uk + ((size_t)b * S_ + s) * H_))[tid];
    float4 v = ((const float4*)Va_w)[tid];
    float acc = v.x * tanhf(u.x + qq.x) + v.y * tanhf(u.y + qq.y)
              + v.z * tanhf(u.z + qq.z) + v.w * tanhf(u.w + qq.w);
    for (int off = 32; off > 0; off >>= 1) acc += __shfl_down(acc, off, 64);
    __shared__ float part[4];
    if ((tid & 63) == 0) part[tid >> 6] = acc;
    __syncthreads();
    if (tid == 0) scores[b * S_ + s] = part[0] + part[1] + part[2] + part[3] + Va_b[0];
}

// softmax over S + ctx = w @ enc (hi/lo out) + attn row
__global__ __launch_bounds__(256) void softctx_k(const float* __restrict__ scores,
                                                 const float* __restrict__ enc,
                                                 ushort_t* __restrict__ ctx_hi,
                                                 ushort_t* __restrict__ ctx_lo,
                                                 float* __restrict__ attn_out, int t)
{
    int hc = blockIdx.x, b = blockIdx.y;
    int tid = threadIdx.x;
    __shared__ float sc[S_], el[S_];
    if (tid < S_) sc[tid] = scores[b * S_ + tid];
    __syncthreads();
    float mx = -1e30f;
    for (int s = 0; s < S_; s++) mx = fmaxf(mx, sc[s]);
    if (tid < S_) el[tid] = expf(sc[tid] - mx);
    __syncthreads();
    float sum = 0.f;
    for (int s = 0; s < S_; s++) sum += el[s];
    float inv = 1.f / sum;
    int h = hc * 256 + tid;
    const float* ep = enc + (size_t)b * S_ * H_ + h;
    float acc = 0.f;
    for (int s = 0; s < S_; s++) acc += el[s] * ep[(size_t)s * H_];
    acc *= inv;
    ushort_t chi = f2bf(acc);
    ctx_hi[(size_t)b * H_ + h] = chi;
    ctx_lo[(size_t)b * H_ + h] = f2bf(acc - bf2f(chi));
    if (hc == 0 && tid < S_) attn_out[((size_t)b * T_ + t) * S_ + tid] = el[tid] * inv;
}

// in-place log_softmax over V per row
__global__ __launch_bounds__(1024) void lsm_k(float* __restrict__ out)
{
    float4* p = (float4*)(out + (size_t)blockIdx.x * V_);
    int tid = threadIdx.x;
    float mx = -1e30f, sm = 0.f;
    for (int v = tid; v < V_ / 4; v += 1024) {
        float4 x = p[v];
        float xs[4] = {x.x, x.y, x.z, x.w};
        #pragma unroll
        for (int j = 0; j < 4; j++) {
            float m2 = fmaxf(mx, xs[j]);
            sm = sm * expf(mx - m2) + expf(xs[j] - m2);
            mx = m2;
        }
    }
    for (int off = 32; off > 0; off >>= 1) {
        float mo = __shfl_down(mx, off, 64);
        float so = __shfl_down(sm, off, 64);
        float m2 = fmaxf(mx, mo);
        sm = sm * expf(mx - m2) + so * expf(mo - m2);
        mx = m2;
    }
    __shared__ float pm[16], ps[16];
    __shared__ float lse_s;
    if ((tid & 63) == 0) { pm[tid >> 6] = mx; ps[tid >> 6] = sm; }
    __syncthreads();
    if (tid == 0) {
        float m = pm[0], s = ps[0];
        for (int i = 1; i < 16; i++) {
            float m2 = fmaxf(m, pm[i]);
            s = s * expf(m - m2) + ps[i] * expf(pm[i] - m2);
            m = m2;
        }
        lse_s = m + logf(s);
    }
    __syncthreads();
    float lse = lse_s;
    for (int v = tid; v < V_ / 4; v += 1024) {
        float4 x = p[v];
        x.x -= lse; x.y -= lse; x.z -= lse; x.w -= lse;
        p[v] = x;
    }
}

// ---------------------------------------------------------------------------
extern "C" void kernel_launch(void* const* d_in, const int* in_sizes, int n_in,
                              void* d_out, int out_size, void* d_ws, size_t ws_size,
                              hipStream_t stream)
{
    (void)in_sizes; (void)n_in; (void)out_size; (void)ws_size;
    const float* enc    = (const float*)d_in[0];
    const float* hidden = (const float*)d_in[1];
    const int*   target = (const int*)d_in[2];
    const float* emb_W  = (const float*)d_in[3];
    const float* Wa_w   = (const float*)d_in[4];
    const float* Wa_b   = (const float*)d_in[5];
    const float* Ua_w   = (const float*)d_in[6];
    const float* Ua_b   = (const float*)d_in[7];
    const float* Va_w   = (const float*)d_in[8];
    const float* Va_b   = (const float*)d_in[9];
    const float* W_ih   = (const float*)d_in[10];
    const float* W_hh   = (const float*)d_in[11];
    const float* b_ih   = (const float*)d_in[12];
    const float* b_hh   = (const float*)d_in[13];
    const float* out_W  = (const float*)d_in[14];
    const float* out_b  = (const float*)d_in[15];

    float* out_logits = (float*)d_out;                       // [B,T,V]
    float* out_hidden = out_logits + (size_t)B_ * T_ * V_;   // [B,H]
    float* out_attn   = out_hidden + (size_t)B_ * H_;        // [B,T,S]

    char* w = (char*)d_ws;
    auto alloc = [&](size_t bytes) { char* p = w; w += (bytes + 255) & ~(size_t)255; return p; };
    // contiguous HI/LO cast destinations (elem offsets within block):
    //   enc 0 | Ua 8388608 | Wih 9437184 | Wc 15728640 (Wa then Whh) | H 19922944 (11*B*H)
    const size_t HIB_ELEMS = 19922944 + (size_t)(T_ + 1) * B_ * H_;   // 20643840
    ushort_t* outW_bf = (ushort_t*)alloc((size_t)V_ * H_ * 2);
    ushort_t* HIb     = (ushort_t*)alloc(HIB_ELEMS * 2);
    ushort_t* LOb     = (ushort_t*)alloc(HIB_ELEMS * 2);
    float*    Uk      = (float*)alloc((size_t)B_ * S_ * H_ * 4);
    ushort_t* E_hi    = (ushort_t*)alloc((size_t)T_ * B_ * H_ * 2);
    ushort_t* E_lo    = (ushort_t*)alloc((size_t)T_ * B_ * H_ * 2);
    float*    giemb   = (float*)alloc((size_t)T_ * B_ * 3 * H_ * 4);
    float*    qgh_part= (float*)alloc((size_t)4 * B_ * 4 * H_ * 4);
    ushort_t* ctx_hi  = (ushort_t*)alloc((size_t)B_ * H_ * 2);
    ushort_t* ctx_lo  = (ushort_t*)alloc((size_t)B_ * H_ * 2);
    float*    scores  = (float*)alloc((size_t)B_ * S_ * 4);

    ushort_t* enc_hi = HIb;                  ushort_t* enc_lo = LOb;
    ushort_t* Ua_hi  = HIb + 8388608;        ushort_t* Ua_lo  = LOb + 8388608;
    ushort_t* Wih_hi = HIb + 9437184;        ushort_t* Wih_lo = LOb + 9437184;
    ushort_t* Wc_hi  = HIb + 15728640;       ushort_t* Wc_lo  = LOb + 15728640;
    ushort_t* H_hi   = HIb + 19922944;       ushort_t* H_lo   = LOb + 19922944;

    // ---- pre-pass ----
    cast_bf16_k<<<V_ * H_ / 8 / 256, 256, 0, stream>>>(out_W, outW_bf, V_ * H_ / 8);
    castall_k<<<2048, 256, 0, stream>>>(enc, Ua_w, W_ih, Wa_w, W_hh, hidden, HIb, LOb);
    gatherhl_k<<<T_ * B_ * H_ / 8 / 256, 256, 0, stream>>>(target, emb_W, E_hi, E_lo);

    // Uk = enc @ Ua^T + Ua_b   (SWZ=1: XCD owns m-rows; nwg=512 -> q=64,r=0)
    gemm_bf<128, 128, 2, true, 0, 1><<<dim3(8, 64, 1), 256, 0, stream>>>(
        enc_hi, enc_lo, H_, Ua_hi, Ua_lo, H_, H_, H_, Ua_b, Uk, H_, 0, 64, 0);
    // giemb = E @ W_ih[:, :H]^T + b_ih   (SWZ=2: XCD owns n-cols; nwg=120 -> q=15,r=0)
    gemm_bf<128, 128, 2, true, 0, 2><<<dim3(24, 5, 1), 256, 0, stream>>>(
        E_hi, E_lo, H_, Wih_hi, Wih_lo, 2 * H_, H_, H_, b_ih, giemb, 3 * H_, 0, 15, 0);

    // ---- recurrence ----
    for (int t = 0; t < T_; t++) {
        float* gi_t = giemb + (size_t)t * B_ * 3 * H_;
        const ushort_t* hh = H_hi + (size_t)t * B_ * H_;
        const ushort_t* hl = H_lo + (size_t)t * B_ * H_;
        // qgh_part[kz] = h @ [Wa ; W_hh]^T  (split-K=4 partials)
        gemm_bf<64, 64, 4, true, 0, 0><<<dim3(4 * H_ / 64, 1, 4), 256, 0, stream>>>(
            hh, hl, H_, Wc_hi, Wc_lo, H_, H_, H_ / 4, nullptr,
            qgh_part, 4 * H_, (size_t)B_ * 4 * H_, 0, 0);
        score_k<<<dim3(S_, B_), 256, 0, stream>>>(Uk, qgh_part, Wa_b, Va_w, Va_b, scores);
        softctx_k<<<dim3(H_ / 256, B_), 256, 0, stream>>>(scores, enc, ctx_hi, ctx_lo, out_attn, t);
        gigru_k<<<H_ / 32, 256, 0, stream>>>(
            ctx_hi, ctx_lo, Wih_hi + H_, Wih_lo + H_, gi_t, qgh_part, b_hh,
            H_hi, H_lo, t, (t == T_ - 1) ? out_hidden : nullptr);
    }

    // ---- deferred logits (SWZ=2; nwg=1250 -> q=156,r=2) ----
    gemm_bf<128, 128, 2, false, 2, 2><<<dim3(250, 5, 1), 256, 0, stream>>>(
        H_hi + (size_t)B_ * H_, nullptr, H_, outW_bf, nullptr, H_, H_, H_,
        out_b, out_logits, 0, 0, 156, 2);
    lsm_k<<<B_ * T_, 1024, 0, stream>>>(out_logits);
}